// Round 3
// baseline (5522.247 us; speedup 1.0000x reference)
//
#include <hip/hip_runtime.h>
#include <hip/hip_bf16.h>

#define LL 128
#define BB 128
#define AA 512
#define II 512
#define HH 1024
#define GG 4096   // 4*H
#define KK 1024   // I+A == H
#define NBLK 64   // blocks in recurrence kernel
#define DPB 16    // h-dims per block

typedef __attribute__((ext_vector_type(8))) short short8;
typedef __attribute__((ext_vector_type(4))) float f32x4;
typedef __attribute__((ext_vector_type(4))) unsigned uint32x4;

static __device__ __forceinline__ unsigned short f2b(float x) {
    union { float f; unsigned u; } v; v.f = x;
    unsigned r = v.u + 0x7fffu + ((v.u >> 16) & 1u);
    return (unsigned short)(r >> 16);
}
static __device__ __forceinline__ float b2f(unsigned short b) {
    union { unsigned u; float f; } v; v.u = ((unsigned)b) << 16; return v.f;
}

typedef const __attribute__((address_space(1))) unsigned char ga_u8;
typedef __attribute__((address_space(3))) unsigned char ls_u8;
static __device__ __forceinline__ void gload_lds16(void* lds_base, const void* gsrc) {
    __builtin_amdgcn_global_load_lds((ga_u8*)gsrc, (ls_u8*)lds_base, 16, 0, 0);
}

// coherent (cross-XCD) 2-byte store: write-through past L1/L2 to the coherence point
static __device__ __forceinline__ void gstore_short_coherent(unsigned short* p, unsigned short v) {
    unsigned v32 = v;
    asm volatile("global_store_short %0, %1, off sc0 sc1" :: "v"(p), "v"(v32) : "memory");
}

// ---------------- pack kernels ----------------
__global__ void build_x_kernel(const float* __restrict__ act, const float* __restrict__ inF,
                               unsigned short* __restrict__ xb) {
    int stride = gridDim.x * blockDim.x;
    for (int idx = blockIdx.x * blockDim.x + threadIdx.x; idx < LL * BB * KK; idx += stride) {
        int i  = idx & (KK - 1);
        int lb = idx >> 10;
        float v;
        if (i < II) v = inF[(lb & (BB - 1)) * II + i];
        else        v = act[(size_t)lb * AA + (i - II)];
        xb[idx] = f2b(v);
    }
}

__global__ void cast_kernel(const float* __restrict__ s, unsigned short* __restrict__ d, int n) {
    int stride = gridDim.x * blockDim.x;
    for (int i = blockIdx.x * blockDim.x + threadIdx.x; i < n; i += stride) d[i] = f2b(s[i]);
}

// ---------------- phase 1: gates_x = xb @ W_ih^T (bf16 out) ----------------
__launch_bounds__(256)
__global__ void gemm_x_kernel(const unsigned short* __restrict__ Ab,   // [16384][1024] bf16
                              const unsigned short* __restrict__ Bb,   // [4096][1024] bf16 (B^T layout)
                              unsigned short* __restrict__ Cb) {       // [16384][4096] bf16
    __shared__ __attribute__((aligned(16))) unsigned short As[128 * 32];
    __shared__ __attribute__((aligned(16))) unsigned short Bs[128 * 32];
    const int tid  = threadIdx.x;
    const int lane = tid & 63;
    const int wid  = tid >> 6;
    const int wr = wid >> 1, wc = wid & 1;
    const int m0 = blockIdx.x * 128, n0 = blockIdx.y * 128;
    const int lrow = lane & 15, lko = (lane >> 4) * 8;
    f32x4 acc[4][4] = {};

    for (int kt = 0; kt < KK / 32; ++kt) {
        const int k0 = kt * 32;
        #pragma unroll
        for (int t = 0; t < 2; ++t) {
            int q   = t * 256 + tid;
            int row = q >> 2;
            int co  = (q & 3) * 8;
            gload_lds16(&As[(t * 256 + wid * 64) * 8], &Ab[(size_t)(m0 + row) * KK + k0 + co]);
            gload_lds16(&Bs[(t * 256 + wid * 64) * 8], &Bb[(size_t)(n0 + row) * KK + k0 + co]);
        }
        __syncthreads();
        short8 af[4], bf[4];
        #pragma unroll
        for (int mi = 0; mi < 4; ++mi)
            af[mi] = *(const short8*)&As[(wr * 64 + mi * 16 + lrow) * 32 + lko];
        #pragma unroll
        for (int ni = 0; ni < 4; ++ni)
            bf[ni] = *(const short8*)&Bs[(wc * 64 + ni * 16 + lrow) * 32 + lko];
        #pragma unroll
        for (int mi = 0; mi < 4; ++mi)
            #pragma unroll
            for (int ni = 0; ni < 4; ++ni)
                acc[mi][ni] = __builtin_amdgcn_mfma_f32_16x16x32_bf16(af[mi], bf[ni], acc[mi][ni], 0, 0, 0);
        __syncthreads();
    }
    #pragma unroll
    for (int mi = 0; mi < 4; ++mi) {
        #pragma unroll
        for (int ni = 0; ni < 4; ++ni) {
            int col = n0 + wc * 64 + ni * 16 + lrow;
            #pragma unroll
            for (int r = 0; r < 4; ++r) {
                int row = m0 + wr * 64 + mi * 16 + (lane >> 4) * 4 + r;
                Cb[(size_t)row * GG + col] = f2b(acc[mi][ni][r]);
            }
        }
    }
}

// ---------------- phase 2: persistent LSTM recurrence, fence-free coherence ----------------
// 64 blocks x 512 threads. Block owns h-dims [16*bid, 16*bid+16) => 64 gate rows
// (4 N-tiles, one per gate). W_hh slice pre-packed in LDS (128 KB). Wave w owns
// batches 16w..16w+15; all 4 gates accumulate in registers. Cross-block h exchange
// uses per-access coherent ops (sc0 sc1 write-through stores, agent-scope relaxed
// atomic loads) so NO buffer_wbl2 / buffer_inv is ever executed in the loop.
__launch_bounds__(512)
__global__ void lstm_kernel(const unsigned short* __restrict__ gx,   // [L*B][4096] bf16
                            const float* __restrict__ Whh,           // [4096][1024] f32
                            const float* __restrict__ bih,
                            const float* __restrict__ bhh,
                            const float* __restrict__ c0,            // [B][H] f32
                            unsigned short* __restrict__ hb,         // [2][B][H] bf16
                            unsigned int* __restrict__ flags,        // [L] zeroed
                            float* __restrict__ out) {               // hs | h_n | c_n
    __shared__ __attribute__((aligned(16))) unsigned short wlds[4 * 32 * 64 * 8]; // 128 KB

    const int tid  = threadIdx.x;
    const int lane = tid & 63;
    const int w    = tid >> 6;          // 8 waves
    const int j0   = blockIdx.x * DPB;
    const int d    = lane & 15;         // dim within block / N index
    const int rgrp = lane >> 4;         // 0..3

    // pack W_hh slice into B-fragment order (once)
    for (int idx = w; idx < 4 * 32; idx += 8) {
        int t = idx >> 5, kt = idx & 31;
        const float* src = &Whh[(size_t)(t * HH + j0 + d) * HH + kt * 32 + rgrp * 8];
        unsigned short* dst = &wlds[(idx * 64 + lane) * 8];
        #pragma unroll
        for (int j = 0; j < 8; ++j) dst[j] = f2b(src[j]);
    }
    float bias_r[4], c_r[4];
    #pragma unroll
    for (int t = 0; t < 4; ++t) bias_r[t] = bih[t * HH + j0 + d] + bhh[t * HH + j0 + d];
    const int b0 = w * 16 + rgrp * 4;   // first of this thread's 4 batches
    #pragma unroll
    for (int r = 0; r < 4; ++r) c_r[r] = c0[(b0 + r) * HH + j0 + d];
    __syncthreads();

    const int arow = w * 16 + d;        // batch row this lane loads for A
    const int ako  = rgrp * 8;

    for (int l = 0; l < LL; ++l) {
        const unsigned short* hr = hb + (size_t)(l & 1) * (BB * HH);
        unsigned short*       hw = hb + (size_t)((l + 1) & 1) * (BB * HH);

        // prefetch gx terms (normal cached loads; read-only data)
        float gxv[4][4];
        #pragma unroll
        for (int r = 0; r < 4; ++r) {
            const unsigned short* gp = &gx[((size_t)l * BB + (b0 + r)) * GG + j0 + d];
            #pragma unroll
            for (int t = 0; t < 4; ++t) gxv[r][t] = b2f(gp[t * HH]);
        }

        // coherent read of h (bypasses stale L1/L2): 32 x 16B per lane as dword atomics
        short8 af[32];
        const unsigned* hp32 = (const unsigned*)(hr + (size_t)arow * HH + ako);
        #pragma unroll
        for (int kt = 0; kt < 32; ++kt) {
            uint32x4 tv;
            #pragma unroll
            for (int q = 0; q < 4; ++q)
                tv[q] = __hip_atomic_load(hp32 + kt * 16 + q, __ATOMIC_RELAXED, __HIP_MEMORY_SCOPE_AGENT);
            af[kt] = __builtin_bit_cast(short8, tv);
        }

        f32x4 acc[4] = {};
        #pragma unroll 4
        for (int kt = 0; kt < 32; ++kt) {
            #pragma unroll
            for (int t = 0; t < 4; ++t) {
                short8 bfr = *(const short8*)&wlds[((t * 32 + kt) * 64 + lane) * 8];
                acc[t] = __builtin_amdgcn_mfma_f32_16x16x32_bf16(af[kt], bfr, acc[t], 0, 0, 0);
            }
        }

        #pragma unroll
        for (int r = 0; r < 4; ++r) {
            float gi = acc[0][r] + gxv[r][0] + bias_r[0];
            float gf = acc[1][r] + gxv[r][1] + bias_r[1];
            float gg = acc[2][r] + gxv[r][2] + bias_r[2];
            float go = acc[3][r] + gxv[r][3] + bias_r[3];
            float ig = 1.f / (1.f + __expf(-gi));
            float fg = 1.f / (1.f + __expf(-gf));
            float og = 1.f / (1.f + __expf(-go));
            float gt = tanhf(gg);
            float c1 = fg * c_r[r] + ig * gt;
            float h1 = og * tanhf(c1);
            c_r[r] = c1;
            gstore_short_coherent(&hw[(b0 + r) * HH + j0 + d], f2b(h1));
            out[((size_t)l * BB + (b0 + r)) * HH + j0 + d] = h1;
            if (l == LL - 1) {
                out[(size_t)LL * BB * HH + (b0 + r) * HH + j0 + d] = h1;
                out[(size_t)LL * BB * HH + BB * HH + (b0 + r) * HH + j0 + d] = c1;
            }
        }

        // --- fence-free grid barrier for step l ---
        asm volatile("s_waitcnt vmcnt(0)" ::: "memory");  // h stores acked at coherence point
        __syncthreads();                                  // whole block done
        if (tid == 0) {
            __hip_atomic_fetch_add(&flags[l], 1u, __ATOMIC_RELAXED, __HIP_MEMORY_SCOPE_AGENT);
            while (__hip_atomic_load(&flags[l], __ATOMIC_RELAXED, __HIP_MEMORY_SCOPE_AGENT) < NBLK) {}
        }
        __syncthreads();
    }
}

extern "C" void kernel_launch(void* const* d_in, const int* in_sizes, int n_in,
                              void* d_out, int out_size, void* d_ws, size_t ws_size,
                              hipStream_t stream) {
    const float* act = (const float*)d_in[0];
    const float* inF = (const float*)d_in[1];
    const float* h0  = (const float*)d_in[2];
    const float* c0  = (const float*)d_in[3];
    const float* Wih = (const float*)d_in[4];
    const float* Whh = (const float*)d_in[5];
    const float* bih = (const float*)d_in[6];
    const float* bhh = (const float*)d_in[7];
    float* out = (float*)d_out;

    char* p = (char*)d_ws;
    unsigned short* xb    = (unsigned short*)p; p += (size_t)LL * BB * KK * 2;   // 33.5 MB
    unsigned short* wih_b = (unsigned short*)p; p += (size_t)GG * KK * 2;        //  8.4 MB
    unsigned short* hb    = (unsigned short*)p; p += (size_t)2 * BB * HH * 2;    //  0.5 MB
    unsigned short* gx    = (unsigned short*)p; p += (size_t)LL * BB * GG * 2;   // 134 MB
    unsigned int*   flags = (unsigned int*)p;   p += LL * sizeof(unsigned int);

    hipMemsetAsync(flags, 0, LL * sizeof(unsigned int), stream);
    build_x_kernel<<<dim3(2048), dim3(256), 0, stream>>>(act, inF, xb);
    cast_kernel<<<dim3(1024), dim3(256), 0, stream>>>(Wih, wih_b, GG * KK);
    cast_kernel<<<dim3(64), dim3(256), 0, stream>>>(h0, hb, BB * HH);
    gemm_x_kernel<<<dim3(128, 32), dim3(256), 0, stream>>>(xb, wih_b, gx);

    void* args[] = { (void*)&gx, (void*)&Whh, (void*)&bih, (void*)&bhh,
                     (void*)&c0, (void*)&hb, (void*)&flags, (void*)&out };
    hipLaunchCooperativeKernel((const void*)lstm_kernel, dim3(NBLK), dim3(512), args, 0, stream);
}

// Round 4
// 1057.618 us; speedup vs baseline: 5.2214x; 5.2214x over previous
//
#include <hip/hip_runtime.h>
#include <hip/hip_bf16.h>

#define LL 128
#define BB 128
#define AA 512
#define II 512
#define HH 1024
#define GG 4096   // 4*H
#define KK 1024   // I+A == H
#define TEAMS 4   // independent batch teams (32 batches each)
#define DG 64     // dim-groups of 16 dims
#define NBLK (TEAMS * DG)   // 256 blocks, 1/CU

typedef __attribute__((ext_vector_type(8))) short short8;
typedef __attribute__((ext_vector_type(4))) float f32x4;
typedef __attribute__((ext_vector_type(4))) unsigned uint32x4;

static __device__ __forceinline__ unsigned short f2b(float x) {
    union { float f; unsigned u; } v; v.f = x;
    unsigned r = v.u + 0x7fffu + ((v.u >> 16) & 1u);
    return (unsigned short)(r >> 16);
}
static __device__ __forceinline__ float b2f(unsigned short b) {
    union { unsigned u; float f; } v; v.u = ((unsigned)b) << 16; return v.f;
}

typedef const __attribute__((address_space(1))) unsigned char ga_u8;
typedef __attribute__((address_space(3))) unsigned char ls_u8;
static __device__ __forceinline__ void gload_lds16(void* lds_base, const void* gsrc) {
    __builtin_amdgcn_global_load_lds((ga_u8*)gsrc, (ls_u8*)lds_base, 16, 0, 0);
}

// coherent (cross-XCD) wide UC accesses: bypass GPU caches, served by memory-side L3
static __device__ __forceinline__ short8 uc_load_b128(const unsigned short* p) {
    short8 r;
    asm volatile("global_load_dwordx4 %0, %1, off sc0 sc1" : "=v"(r) : "v"(p));
    return r;
}
static __device__ __forceinline__ void uc_store_b128(unsigned short* p, uint32x4 v) {
    asm volatile("global_store_dwordx4 %0, %1, off sc0 sc1" :: "v"(p), "v"(v) : "memory");
}

// ---------------- pack kernels ----------------
__global__ void build_x_kernel(const float* __restrict__ act, const float* __restrict__ inF,
                               unsigned short* __restrict__ xb) {
    int stride = gridDim.x * blockDim.x;
    for (int idx = blockIdx.x * blockDim.x + threadIdx.x; idx < LL * BB * KK; idx += stride) {
        int i  = idx & (KK - 1);
        int lb = idx >> 10;
        float v;
        if (i < II) v = inF[(lb & (BB - 1)) * II + i];
        else        v = act[(size_t)lb * AA + (i - II)];
        xb[idx] = f2b(v);
    }
}

__global__ void cast_kernel(const float* __restrict__ s, unsigned short* __restrict__ d, int n) {
    int stride = gridDim.x * blockDim.x;
    for (int i = blockIdx.x * blockDim.x + threadIdx.x; i < n; i += stride) d[i] = f2b(s[i]);
}

// ---------------- phase 1: gates_x = xb @ W_ih^T (bf16 out) ----------------
__launch_bounds__(256)
__global__ void gemm_x_kernel(const unsigned short* __restrict__ Ab,   // [16384][1024] bf16
                              const unsigned short* __restrict__ Bb,   // [4096][1024] bf16 (B^T layout)
                              unsigned short* __restrict__ Cb) {       // [16384][4096] bf16
    __shared__ __attribute__((aligned(16))) unsigned short As[128 * 32];
    __shared__ __attribute__((aligned(16))) unsigned short Bs[128 * 32];
    const int tid  = threadIdx.x;
    const int lane = tid & 63;
    const int wid  = tid >> 6;
    const int wr = wid >> 1, wc = wid & 1;
    const int m0 = blockIdx.x * 128, n0 = blockIdx.y * 128;
    const int lrow = lane & 15, lko = (lane >> 4) * 8;
    f32x4 acc[4][4] = {};

    for (int kt = 0; kt < KK / 32; ++kt) {
        const int k0 = kt * 32;
        #pragma unroll
        for (int t = 0; t < 2; ++t) {
            int q   = t * 256 + tid;
            int row = q >> 2;
            int co  = (q & 3) * 8;
            gload_lds16(&As[(t * 256 + wid * 64) * 8], &Ab[(size_t)(m0 + row) * KK + k0 + co]);
            gload_lds16(&Bs[(t * 256 + wid * 64) * 8], &Bb[(size_t)(n0 + row) * KK + k0 + co]);
        }
        __syncthreads();
        short8 af[4], bf[4];
        #pragma unroll
        for (int mi = 0; mi < 4; ++mi)
            af[mi] = *(const short8*)&As[(wr * 64 + mi * 16 + lrow) * 32 + lko];
        #pragma unroll
        for (int ni = 0; ni < 4; ++ni)
            bf[ni] = *(const short8*)&Bs[(wc * 64 + ni * 16 + lrow) * 32 + lko];
        #pragma unroll
        for (int mi = 0; mi < 4; ++mi)
            #pragma unroll
            for (int ni = 0; ni < 4; ++ni)
                acc[mi][ni] = __builtin_amdgcn_mfma_f32_16x16x32_bf16(af[mi], bf[ni], acc[mi][ni], 0, 0, 0);
        __syncthreads();
    }
    #pragma unroll
    for (int mi = 0; mi < 4; ++mi) {
        #pragma unroll
        for (int ni = 0; ni < 4; ++ni) {
            int col = n0 + wc * 64 + ni * 16 + lrow;
            #pragma unroll
            for (int r = 0; r < 4; ++r) {
                int row = m0 + wr * 64 + mi * 16 + (lane >> 4) * 4 + r;
                Cb[(size_t)row * GG + col] = f2b(acc[mi][ni][r]);
            }
        }
    }
}

// ---------------- phase 2: persistent LSTM recurrence ----------------
// 256 blocks = 4 teams (32 batches) x 64 dim-groups (16 dims). Teams fully
// independent (own barrier, own h rows). 8 waves = 2 M-tiles x 4 K-slices;
// 4 gate chains in-register per wave, K-partials reduced via padded LDS.
// Cross-block h exchange: wide UC (sc0 sc1) loads/stores only — NO fences,
// NO L2 writeback/invalidate in the loop.
__launch_bounds__(512)
__global__ void lstm_kernel(const unsigned short* __restrict__ gx,   // [L*B][4096] bf16
                            const float* __restrict__ Whh,           // [4096][1024] f32
                            const float* __restrict__ bih,
                            const float* __restrict__ bhh,
                            const float* __restrict__ c0,            // [B][H] f32
                            unsigned short* __restrict__ hb,         // [2][B][H] bf16
                            unsigned int* __restrict__ flags,        // [TEAMS*L] zeroed
                            float* __restrict__ out) {               // hs | h_n | c_n
    __shared__ __attribute__((aligned(16))) unsigned short wlds[4 * 32 * 64 * 8]; // 128 KB
    __shared__ float redbuf[4 * 64 * 17];                                         // 17 KB, padded
    __shared__ __attribute__((aligned(16))) unsigned short hbuf[32 * 16];         // 1 KB

    const int tid  = threadIdx.x;
    const int lane = tid & 63;
    const int w    = tid >> 6;          // 8 waves
    const int mt   = w >> 2;            // M-tile (16 batches)
    const int ks   = w & 3;             // K-slice (256)
    const int dg   = blockIdx.x & (DG - 1);
    const int mg   = blockIdx.x >> 6;   // team
    const int j0   = dg * 16;
    const int d    = lane & 15;
    const int rgrp = lane >> 4;

    // pack W_hh slice [4 gates][16 dims] into B-fragment order (once)
    for (int idx = w; idx < 4 * 32; idx += 8) {
        int t = idx >> 5, kt = idx & 31;
        const float* src = &Whh[(size_t)(t * HH + j0 + d) * HH + kt * 32 + rgrp * 8];
        unsigned short* dst = &wlds[(idx * 64 + lane) * 8];
        #pragma unroll
        for (int j = 0; j < 8; ++j) dst[j] = f2b(src[j]);
    }
    float bias_r[4], c_r[4];
    const int brow = mg * 32 + mt * 16 + rgrp * 4;   // first batch of this thread's quad
    #pragma unroll
    for (int t = 0; t < 4; ++t) bias_r[t] = bih[t * HH + j0 + d] + bhh[t * HH + j0 + d];
    #pragma unroll
    for (int r = 0; r < 4; ++r) c_r[r] = c0[(brow + r) * HH + j0 + d];
    __syncthreads();

    for (int l = 0; l < LL; ++l) {
        const unsigned short* hr = hb + (size_t)(l & 1) * (BB * HH);
        unsigned short*       hw = hb + (size_t)((l + 1) & 1) * (BB * HH);

        // gx prefetch (cached path; only gate-math waves need it)
        float gxv[4][4];
        if (ks == 0) {
            #pragma unroll
            for (int r = 0; r < 4; ++r) {
                const unsigned short* gp = &gx[((size_t)l * BB + (brow + r)) * GG + j0 + d];
                #pragma unroll
                for (int t = 0; t < 4; ++t) gxv[r][t] = b2f(gp[t * HH]);
            }
        }

        // coherent h read: 8 wide UC loads per lane (16 rows x 256 K per wave)
        short8 af[8];
        const unsigned short* hp = hr + (size_t)(mg * 32 + mt * 16 + d) * HH + ks * 256 + rgrp * 8;
        #pragma unroll
        for (int j = 0; j < 8; ++j) af[j] = uc_load_b128(hp + j * 32);
        asm volatile("s_waitcnt vmcnt(0)" ::: "memory");
        __builtin_amdgcn_sched_barrier(0);

        f32x4 acc[4] = {};
        #pragma unroll
        for (int j = 0; j < 8; ++j) {
            #pragma unroll
            for (int t = 0; t < 4; ++t) {
                short8 bfr = *(const short8*)&wlds[((t * 32 + ks * 8 + j) * 64 + lane) * 8];
                acc[t] = __builtin_amdgcn_mfma_f32_16x16x32_bf16(af[j], bfr, acc[t], 0, 0, 0);
            }
        }

        // cross-wave K reduction: ks{1,3} -> buf, ks{0,2} absorb, ks2 -> buf, ks0 final
        float* slot0 = &redbuf[(size_t)(mt * 2 + 0) * 64 * 17 + lane * 17];
        float* slot1 = &redbuf[(size_t)(mt * 2 + 1) * 64 * 17 + lane * 17];
        if (ks == 1) {
            #pragma unroll
            for (int t = 0; t < 4; ++t)
                #pragma unroll
                for (int r = 0; r < 4; ++r) slot0[t * 4 + r] = acc[t][r];
        }
        if (ks == 3) {
            #pragma unroll
            for (int t = 0; t < 4; ++t)
                #pragma unroll
                for (int r = 0; r < 4; ++r) slot1[t * 4 + r] = acc[t][r];
        }
        __syncthreads();
        if (ks == 0) {
            #pragma unroll
            for (int t = 0; t < 4; ++t)
                #pragma unroll
                for (int r = 0; r < 4; ++r) acc[t][r] += slot0[t * 4 + r];
        }
        if (ks == 2) {
            #pragma unroll
            for (int t = 0; t < 4; ++t)
                #pragma unroll
                for (int r = 0; r < 4; ++r) {
                    float v = acc[t][r] + slot1[t * 4 + r];
                    slot1[t * 4 + r] = v;
                }
        }
        __syncthreads();

        if (ks == 0) {
            #pragma unroll
            for (int t = 0; t < 4; ++t)
                #pragma unroll
                for (int r = 0; r < 4; ++r) acc[t][r] += slot1[t * 4 + r];

            #pragma unroll
            for (int r = 0; r < 4; ++r) {
                float gi = acc[0][r] + gxv[r][0] + bias_r[0];
                float gf = acc[1][r] + gxv[r][1] + bias_r[1];
                float gg = acc[2][r] + gxv[r][2] + bias_r[2];
                float go = acc[3][r] + gxv[r][3] + bias_r[3];
                float ig = 1.f / (1.f + __expf(-gi));
                float fg = 1.f / (1.f + __expf(-gf));
                float og = 1.f / (1.f + __expf(-go));
                float gt = tanhf(gg);
                float c1 = fg * c_r[r] + ig * gt;
                float h1 = og * tanhf(c1);
                c_r[r] = c1;
                hbuf[(mt * 16 + rgrp * 4 + r) * 16 + d] = f2b(h1);
                out[((size_t)l * BB + (brow + r)) * HH + j0 + d] = h1;
                if (l == LL - 1) {
                    out[(size_t)LL * BB * HH + (brow + r) * HH + j0 + d] = h1;
                    out[(size_t)LL * BB * HH + BB * HH + (brow + r) * HH + j0 + d] = c1;
                }
            }
        }
        __syncthreads();   // hbuf complete

        // wave 0: line-dense coherent h store (32 rows x 32 B, as 16 B dwordx4)
        if (w == 0) {
            int row = lane >> 1, half = lane & 1;
            uint32x4 hv = *(const uint32x4*)&hbuf[row * 16 + half * 8];
            uc_store_b128(&hw[(size_t)(mg * 32 + row) * HH + j0 + half * 8], hv);
            asm volatile("s_waitcnt vmcnt(0)" ::: "memory");   // h acked at coherence point
        }
        __syncthreads();

        // team barrier (64 blocks), fence-free
        if (tid == 0) {
            unsigned int* fp = &flags[mg * LL + l];
            __hip_atomic_fetch_add(fp, 1u, __ATOMIC_RELAXED, __HIP_MEMORY_SCOPE_AGENT);
            while (__hip_atomic_load(fp, __ATOMIC_RELAXED, __HIP_MEMORY_SCOPE_AGENT) < DG) {}
        }
        __syncthreads();
    }
}

extern "C" void kernel_launch(void* const* d_in, const int* in_sizes, int n_in,
                              void* d_out, int out_size, void* d_ws, size_t ws_size,
                              hipStream_t stream) {
    const float* act = (const float*)d_in[0];
    const float* inF = (const float*)d_in[1];
    const float* h0  = (const float*)d_in[2];
    const float* c0  = (const float*)d_in[3];
    const float* Wih = (const float*)d_in[4];
    const float* Whh = (const float*)d_in[5];
    const float* bih = (const float*)d_in[6];
    const float* bhh = (const float*)d_in[7];
    float* out = (float*)d_out;

    char* p = (char*)d_ws;
    unsigned short* xb    = (unsigned short*)p; p += (size_t)LL * BB * KK * 2;   // 33.5 MB
    unsigned short* wih_b = (unsigned short*)p; p += (size_t)GG * KK * 2;        //  8.4 MB
    unsigned short* hb    = (unsigned short*)p; p += (size_t)2 * BB * HH * 2;    //  0.5 MB
    unsigned short* gx    = (unsigned short*)p; p += (size_t)LL * BB * GG * 2;   // 134 MB
    unsigned int*   flags = (unsigned int*)p;   p += TEAMS * LL * sizeof(unsigned int);

    hipMemsetAsync(flags, 0, TEAMS * LL * sizeof(unsigned int), stream);
    build_x_kernel<<<dim3(2048), dim3(256), 0, stream>>>(act, inF, xb);
    cast_kernel<<<dim3(1024), dim3(256), 0, stream>>>(Wih, wih_b, GG * KK);
    cast_kernel<<<dim3(64), dim3(256), 0, stream>>>(h0, hb, BB * HH);
    gemm_x_kernel<<<dim3(128, 32), dim3(256), 0, stream>>>(xb, wih_b, gx);

    void* args[] = { (void*)&gx, (void*)&Whh, (void*)&bih, (void*)&bhh,
                     (void*)&c0, (void*)&hb, (void*)&flags, (void*)&out };
    hipLaunchCooperativeKernel((const void*)lstm_kernel, dim3(NBLK), dim3(512), args, 0, stream);
}